// Round 1
// baseline (207.188 us; speedup 1.0000x reference)
//
#include <hip/hip_runtime.h>

#define SEQ   2048
#define BATCH 32
#define INF   256
#define NST   512
#define OUTF  256
#define CLEN  32
#define NCH   (SEQ / CLEN)   /* 64 chunks */

typedef __bf16 bf16;
typedef __bf16 bf16x8 __attribute__((ext_vector_type(8)));
typedef float  f32x4  __attribute__((ext_vector_type(4)));

// ---------------------------------------------------------------------------
// K1: lambda = exp(-exp(ll)); lamL = lambda^CLEN; B' = gamma*B (bf16); C (bf16)
// ---------------------------------------------------------------------------
__global__ void k_prep(const float* __restrict__ ll,
                       const float* __restrict__ Bm,
                       const float* __restrict__ Cm,
                       float* __restrict__ lam,
                       float* __restrict__ lamL,
                       bf16* __restrict__ Bb,
                       bf16* __restrict__ Cb) {
  int i = blockIdx.x * 256 + threadIdx.x;
  if (i < NST) {
    float lmb = expf(-expf(ll[i]));
    lam[i] = lmb;
    float p = lmb;
#pragma unroll
    for (int q = 0; q < 5; ++q) p *= p;   // lambda^32
    lamL[i] = p;
  }
  if (i < NST * INF) {
    int n = i >> 8;                        // row of B (state index)
    float lmb = expf(-expf(ll[n]));
    float g = sqrtf(1.0f - lmb * lmb + 1e-7f);
    Bb[i] = (bf16)(Bm[i] * g);
  }
  if (i < OUTF * NST) {
    Cb[i] = (bf16)(Cm[i]);
  }
}

// ---------------------------------------------------------------------------
// K2/K4: per (chunk, batch) block.
//   GEMM1 (MFMA bf16): b_t[t][n] = sum_i x[t][i] * B'[n][i]   -> LDS f32
//   scan over t (thread-per-n)
//   FULL=0: write chunk carry Z[c][b][n]
//   FULL=1: start from S0, states -> bf16 in-place (XOR-staggered), GEMM2 -> out
// ---------------------------------------------------------------------------
template <int FULL>
__global__ __launch_bounds__(512)
void k_scan(const float* __restrict__ x,
            const bf16* __restrict__ Bb,
            const bf16* __restrict__ Cb,
            const float* __restrict__ lam,
            const float* __restrict__ S0,
            float* __restrict__ Z,
            float* __restrict__ out,
            float* __restrict__ fin) {
  __shared__ bf16  xs[CLEN * INF];   // 16 KB, XOR-swizzled rows
  __shared__ float bs[CLEN * NST];   // 64 KB, b_seq f32; rows rewritten as bf16 states (FULL)

  const int c = blockIdx.x, b = blockIdx.y;
  const int tid = threadIdx.x;
  const int wid = tid >> 6, lane = tid & 63;
  const int rl = lane & 15, kg = lane >> 4;

  // ---- stage x chunk: f32 -> bf16 into LDS, swizzle byte ^= (row&7)<<4
  {
    const float* xp = x + ((size_t)(c * CLEN) * BATCH + b) * INF;
#pragma unroll
    for (int rep = 0; rep < 4; ++rep) {
      int slot = rep * 512 + tid;          // 0..2047 float4 slots
      int row = slot >> 6, col4 = slot & 63;
      float4 v = *(const float4*)(xp + (size_t)row * (BATCH * INF) + col4 * 4);
      union { bf16 h[4]; unsigned long long u; } pk;
      pk.h[0] = (bf16)v.x; pk.h[1] = (bf16)v.y;
      pk.h[2] = (bf16)v.z; pk.h[3] = (bf16)v.w;
      int byte = (row * (INF * 2) + col4 * 8) ^ ((row & 7) << 4);
      *(unsigned long long*)((char*)xs + byte) = pk.u;
    }
  }
  __syncthreads();

  // ---- GEMM1: wave w owns n-panel [w*64, w*64+64)
  {
    const int n0 = wid * 64;
    f32x4 acc[2][4] = {};
#pragma unroll
    for (int k0 = 0; k0 < INF; k0 += 32) {
      bf16x8 af[2], bfr[4];
#pragma unroll
      for (int mt = 0; mt < 2; ++mt) {
        int row = mt * 16 + rl;
        int byte = (row * (INF * 2) + (k0 + kg * 8) * 2) ^ ((row & 7) << 4);
        af[mt] = *(const bf16x8*)((const char*)xs + byte);
      }
#pragma unroll
      for (int nt = 0; nt < 4; ++nt)
        bfr[nt] = *(const bf16x8*)(Bb + (size_t)(n0 + nt * 16 + rl) * INF + k0 + kg * 8);
#pragma unroll
      for (int mt = 0; mt < 2; ++mt)
#pragma unroll
        for (int nt = 0; nt < 4; ++nt)
          acc[mt][nt] = __builtin_amdgcn_mfma_f32_16x16x32_bf16(af[mt], bfr[nt], acc[mt][nt], 0, 0, 0);
    }
    // epilogue: fragments -> bs f32 (row = t, col = n)
#pragma unroll
    for (int mt = 0; mt < 2; ++mt)
#pragma unroll
      for (int nt = 0; nt < 4; ++nt)
#pragma unroll
        for (int r = 0; r < 4; ++r)
          bs[(mt * 16 + kg * 4 + r) * NST + n0 + nt * 16 + rl] = acc[mt][nt][r];
  }
  __syncthreads();

  // ---- scan: thread n = tid (512 threads)
  {
    const int n = tid;
    const float lmb = lam[n];
    float st = 0.0f;
    if (FULL) st = S0[((size_t)c * BATCH + b) * NST + n];
#pragma unroll
    for (int t = 0; t < CLEN; ++t) {
      st = fmaf(lmb, st, bs[t * NST + n]);   // read row t (all threads) ...
      if (FULL) {
        __syncthreads();                     // ... then everyone writes row t
        int byte = (t * (NST * 4) + n * 2) ^ ((t & 7) << 4);
        *(bf16*)((char*)bs + byte) = (bf16)st;
      }
    }
    if (FULL) {
      if (c == NCH - 1) fin[(size_t)b * NST + n] = st;
    } else {
      Z[((size_t)c * BATCH + b) * NST + n] = st;
    }
  }
  if (!FULL) return;
  __syncthreads();

  // ---- GEMM2: out[t][o] = sum_n states[t][n] * C[o][n]; wave w owns o-panel [w*32,..)
  {
    const int o0 = wid * 32;
    f32x4 acc[2][2] = {};
#pragma unroll
    for (int k0 = 0; k0 < NST; k0 += 32) {
      bf16x8 af[2], cf[2];
#pragma unroll
      for (int mt = 0; mt < 2; ++mt) {
        int row = mt * 16 + rl;
        int byte = (row * (NST * 4) + (k0 + kg * 8) * 2) ^ ((row & 7) << 4);
        af[mt] = *(const bf16x8*)((const char*)bs + byte);
      }
#pragma unroll
      for (int ot = 0; ot < 2; ++ot)
        cf[ot] = *(const bf16x8*)(Cb + (size_t)(o0 + ot * 16 + rl) * NST + k0 + kg * 8);
#pragma unroll
      for (int mt = 0; mt < 2; ++mt)
#pragma unroll
        for (int ot = 0; ot < 2; ++ot)
          acc[mt][ot] = __builtin_amdgcn_mfma_f32_16x16x32_bf16(af[mt], cf[ot], acc[mt][ot], 0, 0, 0);
    }
#pragma unroll
    for (int mt = 0; mt < 2; ++mt)
#pragma unroll
      for (int ot = 0; ot < 2; ++ot)
#pragma unroll
        for (int r = 0; r < 4; ++r) {
          int t = mt * 16 + kg * 4 + r;
          int o = o0 + ot * 16 + rl;
          out[(((size_t)(c * CLEN + t)) * BATCH + b) * OUTF + o] = acc[mt][ot][r];
        }
  }
}

// ---------------------------------------------------------------------------
// K3: exclusive prefix over chunks:  S0[c] = lamL*S0[c-1] + Z[c-1],  S0[0]=0
// ---------------------------------------------------------------------------
__global__ __launch_bounds__(512)
void k_chain(const float* __restrict__ Z, const float* __restrict__ lamL,
             float* __restrict__ S0) {
  const int b = blockIdx.x, n = threadIdx.x;
  const float lL = lamL[n];
  float z[NCH];
#pragma unroll
  for (int c = 0; c < NCH; ++c)
    z[c] = Z[((size_t)c * BATCH + b) * NST + n];
  float s = 0.0f;
#pragma unroll
  for (int c = 0; c < NCH; ++c) {
    S0[((size_t)c * BATCH + b) * NST + n] = s;
    s = fmaf(lL, s, z[c]);
  }
}

// ---------------------------------------------------------------------------
extern "C" void kernel_launch(void* const* d_in, const int* in_sizes, int n_in,
                              void* d_out, int out_size, void* d_ws, size_t ws_size,
                              hipStream_t stream) {
  const float* x  = (const float*)d_in[0];
  const float* ll = (const float*)d_in[1];
  const float* Bm = (const float*)d_in[2];
  const float* Cm = (const float*)d_in[3];

  char* ws = (char*)d_ws;
  float* lam  = (float*)(ws);
  float* lamL = (float*)(ws + 2048);
  bf16*  Bb   = (bf16*)(ws + 4096);
  bf16*  Cb   = (bf16*)(ws + 4096 + NST * INF * 2);
  float* Z    = (float*)(ws + 4096 + NST * INF * 2 + OUTF * NST * 2);
  float* S0   = (float*)((char*)Z + (size_t)NCH * BATCH * NST * 4);
  // total ws use: ~8.9 MB

  float* out = (float*)d_out;
  float* fin = out + (size_t)SEQ * BATCH * OUTF;

  k_prep<<<dim3(512), dim3(256), 0, stream>>>(ll, Bm, Cm, lam, lamL, Bb, Cb);
  k_scan<0><<<dim3(NCH, BATCH), dim3(512), 0, stream>>>(x, Bb, Cb, lam, S0, Z, out, fin);
  k_chain<<<dim3(BATCH), dim3(512), 0, stream>>>(Z, lamL, S0);
  k_scan<1><<<dim3(NCH, BATCH), dim3(512), 0, stream>>>(x, Bb, Cb, lam, S0, Z, out, fin);
}

// Round 2
// 155.348 us; speedup vs baseline: 1.3337x; 1.3337x over previous
//
#include <hip/hip_runtime.h>

#define SEQ   2048
#define BATCH 32
#define INF   256
#define NST   512
#define OUTF  256
#define CLEN  32
#define NCH   (SEQ / CLEN)   /* 64 chunks */

typedef __bf16 bf16;
typedef __bf16 bf16x8 __attribute__((ext_vector_type(8)));
typedef float  f32x4  __attribute__((ext_vector_type(4)));

// ---------------------------------------------------------------------------
// K1: lambda = exp(-exp(ll)); lamL = lambda^CLEN; B' = gamma*B (bf16); C (bf16)
// ---------------------------------------------------------------------------
__global__ void k_prep(const float* __restrict__ ll,
                       const float* __restrict__ Bm,
                       const float* __restrict__ Cm,
                       float* __restrict__ lam,
                       float* __restrict__ lamL,
                       bf16* __restrict__ Bb,
                       bf16* __restrict__ Cb) {
  int i = blockIdx.x * 256 + threadIdx.x;
  if (i < NST) {
    float lmb = expf(-expf(ll[i]));
    lam[i] = lmb;
    float p = lmb;
#pragma unroll
    for (int q = 0; q < 5; ++q) p *= p;   // lambda^32
    lamL[i] = p;
  }
  if (i < NST * INF) {
    int n = i >> 8;
    float lmb = expf(-expf(ll[n]));
    float g = sqrtf(1.0f - lmb * lmb + 1e-7f);
    Bb[i] = (bf16)(Bm[i] * g);
  }
  if (i < OUTF * NST) {
    Cb[i] = (bf16)(Cm[i]);
  }
}

// ---------------------------------------------------------------------------
// shared helpers: stage x chunk to LDS (bf16, XOR swizzle), GEMM1 -> bsh bf16
// bsh layout: [t][n] bf16, byte = (t*1024 + n*2) ^ ((t&7)<<4)
// ---------------------------------------------------------------------------
__device__ __forceinline__ void stage_x(const float* __restrict__ xp,
                                        char* xs, int tid) {
#pragma unroll
  for (int rep = 0; rep < 4; ++rep) {
    int slot = rep * 512 + tid;          // 0..2047 float4 slots
    int row = slot >> 6, col4 = slot & 63;
    float4 v = *(const float4*)(xp + (size_t)row * (BATCH * INF) + col4 * 4);
    union { bf16 h[4]; unsigned long long u; } pk;
    pk.h[0] = (bf16)v.x; pk.h[1] = (bf16)v.y;
    pk.h[2] = (bf16)v.z; pk.h[3] = (bf16)v.w;
    int byte = (row * (INF * 2) + col4 * 8) ^ ((row & 7) << 4);
    *(unsigned long long*)(xs + byte) = pk.u;
  }
}

__device__ __forceinline__ void gemm1(const char* xs,
                                      const bf16* __restrict__ Bb,
                                      char* bsh, int wid, int rl, int kg) {
  const int n0 = wid * 64;
  f32x4 acc[2][4] = {};
#pragma unroll
  for (int k0 = 0; k0 < INF; k0 += 32) {
    bf16x8 af[2], bfr[4];
#pragma unroll
    for (int mt = 0; mt < 2; ++mt) {
      int row = mt * 16 + rl;
      int byte = (row * (INF * 2) + (k0 + kg * 8) * 2) ^ ((row & 7) << 4);
      af[mt] = *(const bf16x8*)(xs + byte);
    }
#pragma unroll
    for (int nt = 0; nt < 4; ++nt)
      bfr[nt] = *(const bf16x8*)(Bb + (size_t)(n0 + nt * 16 + rl) * INF + k0 + kg * 8);
#pragma unroll
    for (int mt = 0; mt < 2; ++mt)
#pragma unroll
      for (int nt = 0; nt < 4; ++nt)
        acc[mt][nt] = __builtin_amdgcn_mfma_f32_16x16x32_bf16(af[mt], bfr[nt], acc[mt][nt], 0, 0, 0);
  }
#pragma unroll
  for (int mt = 0; mt < 2; ++mt)
#pragma unroll
    for (int nt = 0; nt < 4; ++nt)
#pragma unroll
      for (int r = 0; r < 4; ++r) {
        int t = mt * 16 + kg * 4 + r;
        int n = n0 + nt * 16 + rl;
        int byte = (t * (NST * 2) + n * 2) ^ ((t & 7) << 4);
        *(bf16*)(bsh + byte) = (bf16)acc[mt][nt][r];
      }
}

// ---------------------------------------------------------------------------
// PASS1: GEMM1 -> bsh; optional spill bsh -> bbuf (linear layout); scan -> Z
// LDS 48KB -> 3 blocks/CU. No in-loop barriers.
// ---------------------------------------------------------------------------
template <int USEB>
__global__ __launch_bounds__(512)
void k_pass1(const float* __restrict__ x, const bf16* __restrict__ Bb,
             const float* __restrict__ lam, float* __restrict__ Z,
             bf16* __restrict__ bbuf) {
  __shared__ __align__(16) char xs[CLEN * INF * 2];   // 16KB
  __shared__ __align__(16) char bsh[CLEN * NST * 2];  // 32KB
  const int c = blockIdx.x, b = blockIdx.y, tid = threadIdx.x;
  const int wid = tid >> 6, lane = tid & 63, rl = lane & 15, kg = lane >> 4;

  stage_x(x + ((size_t)(c * CLEN) * BATCH + b) * INF, xs, tid);
  __syncthreads();
  gemm1(xs, Bb, bsh, wid, rl, kg);
  __syncthreads();

  if (USEB) {  // spill b_seq (de-swizzled) for PASS2: coalesced 16B stores
    uint4* dst = (uint4*)(bbuf + (size_t)(c * BATCH + b) * CLEN * NST);
#pragma unroll
    for (int q = 0; q < 4; ++q) {
      int slot = q * 512 + tid;          // 16B slots, 0..2047
      int t = slot >> 6;
      dst[slot] = *(const uint4*)(bsh + ((slot * 16) ^ ((t & 7) << 4)));
    }
  }

  // scan (barrier-free): thread n, dependent FMA chain, LDS reads prefetchable
  const int n = tid;
  const float lmb = lam[n];
  float st = 0.0f;
#pragma unroll
  for (int t = 0; t < CLEN; ++t) {
    int byte = (t * (NST * 2) + n * 2) ^ ((t & 7) << 4);
    st = fmaf(lmb, st, (float)*(const bf16*)(bsh + byte));
  }
  Z[((size_t)c * BATCH + b) * NST + n] = st;
}

// ---------------------------------------------------------------------------
// K3: exclusive prefix over chunks:  S0[c] = lamL*S0[c-1] + Z[c-1],  S0[0]=0
// ---------------------------------------------------------------------------
__global__ __launch_bounds__(512)
void k_chain(const float* __restrict__ Z, const float* __restrict__ lamL,
             float* __restrict__ S0) {
  const int b = blockIdx.x, n = threadIdx.x;
  const float lL = lamL[n];
  float z[NCH];
#pragma unroll
  for (int c = 0; c < NCH; ++c)
    z[c] = Z[((size_t)c * BATCH + b) * NST + n];
  float s = 0.0f;
#pragma unroll
  for (int c = 0; c < NCH; ++c) {
    S0[((size_t)c * BATCH + b) * NST + n] = s;
    s = fmaf(lL, s, z[c]);
  }
}

// ---------------------------------------------------------------------------
// PASS2: scan (from S0, b from bbuf-global or recomputed) -> ss bf16 (swz),
//        GEMM2 from ss -> out. USEB: LDS 32KB -> 4 blocks/CU, no GEMM1.
// ---------------------------------------------------------------------------
template <int USEB>
__global__ __launch_bounds__(512)
void k_pass2(const float* __restrict__ x, const bf16* __restrict__ Bb,
             const bf16* __restrict__ Cb, const float* __restrict__ lam,
             const float* __restrict__ S0, const bf16* __restrict__ bbuf,
             float* __restrict__ out, float* __restrict__ fin) {
  constexpr int SS_OFF = USEB ? 0 : (CLEN * INF * 2 + CLEN * NST * 2);
  __shared__ __align__(16) char smem[SS_OFF + CLEN * NST * 2];
  char* ss = smem + SS_OFF;

  const int c = blockIdx.x, b = blockIdx.y, tid = threadIdx.x;
  const int wid = tid >> 6, lane = tid & 63, rl = lane & 15, kg = lane >> 4;

  if (!USEB) {
    char* xs = smem;
    char* bsh = smem + CLEN * INF * 2;
    stage_x(x + ((size_t)(c * CLEN) * BATCH + b) * INF, xs, tid);
    __syncthreads();
    gemm1(xs, Bb, bsh, wid, rl, kg);
    __syncthreads();
  }

  // scan (barrier-free)
  {
    const int n = tid;
    const float lmb = lam[n];
    float st = S0[((size_t)c * BATCH + b) * NST + n];
    const bf16* bp = bbuf + (size_t)(c * BATCH + b) * CLEN * NST + n;
    const char* bsh = smem + CLEN * INF * 2;
#pragma unroll
    for (int t = 0; t < CLEN; ++t) {
      float bv;
      if (USEB) {
        bv = (float)bp[t * NST];                       // coalesced, L3-warm
      } else {
        int byte = (t * (NST * 2) + n * 2) ^ ((t & 7) << 4);
        bv = (float)*(const bf16*)(bsh + byte);
      }
      st = fmaf(lmb, st, bv);
      int sb = (t * (NST * 2) + n * 2) ^ ((t & 7) << 4);
      *(bf16*)(ss + sb) = (bf16)st;
    }
    if (c == NCH - 1) fin[(size_t)b * NST + n] = st;
  }
  __syncthreads();

  // GEMM2: out[t][o] = sum_n states[t][n] * C[o][n]
  {
    const int o0 = wid * 32;
    f32x4 acc[2][2] = {};
#pragma unroll
    for (int k0 = 0; k0 < NST; k0 += 32) {
      bf16x8 af[2], cf[2];
#pragma unroll
      for (int mt = 0; mt < 2; ++mt) {
        int t = mt * 16 + rl;
        int byte = (t * (NST * 2) + (k0 + kg * 8) * 2) ^ ((t & 7) << 4);
        af[mt] = *(const bf16x8*)(ss + byte);
      }
#pragma unroll
      for (int ot = 0; ot < 2; ++ot)
        cf[ot] = *(const bf16x8*)(Cb + (size_t)(o0 + ot * 16 + rl) * NST + k0 + kg * 8);
#pragma unroll
      for (int mt = 0; mt < 2; ++mt)
#pragma unroll
        for (int ot = 0; ot < 2; ++ot)
          acc[mt][ot] = __builtin_amdgcn_mfma_f32_16x16x32_bf16(af[mt], cf[ot], acc[mt][ot], 0, 0, 0);
    }
#pragma unroll
    for (int mt = 0; mt < 2; ++mt)
#pragma unroll
      for (int ot = 0; ot < 2; ++ot)
#pragma unroll
        for (int r = 0; r < 4; ++r) {
          int t = mt * 16 + kg * 4 + r;
          int o = o0 + ot * 16 + rl;
          out[(((size_t)(c * CLEN + t)) * BATCH + b) * OUTF + o] = acc[mt][ot][r];
        }
  }
}

// ---------------------------------------------------------------------------
extern "C" void kernel_launch(void* const* d_in, const int* in_sizes, int n_in,
                              void* d_out, int out_size, void* d_ws, size_t ws_size,
                              hipStream_t stream) {
  const float* x  = (const float*)d_in[0];
  const float* ll = (const float*)d_in[1];
  const float* Bm = (const float*)d_in[2];
  const float* Cm = (const float*)d_in[3];

  char* ws = (char*)d_ws;
  float* lam  = (float*)(ws);
  float* lamL = (float*)(ws + 2048);
  bf16*  Bb   = (bf16*)(ws + 4096);
  bf16*  Cb   = (bf16*)(ws + 4096 + NST * INF * 2);
  float* Z    = (float*)(ws + 4096 + NST * INF * 2 + OUTF * NST * 2);
  float* S0   = (float*)((char*)Z + (size_t)NCH * BATCH * NST * 4);
  bf16*  bbuf = (bf16*)((char*)S0 + (size_t)NCH * BATCH * NST * 4);
  const size_t NEED = 4096 + (size_t)NST * INF * 2 + (size_t)OUTF * NST * 2
                    + 2 * (size_t)NCH * BATCH * NST * 4
                    + (size_t)SEQ * BATCH * NST * 2;   // ~76 MB

  float* out = (float*)d_out;
  float* fin = out + (size_t)SEQ * BATCH * OUTF;

  const int useb = (ws_size >= NEED) ? 1 : 0;

  k_prep<<<dim3(512), dim3(256), 0, stream>>>(ll, Bm, Cm, lam, lamL, Bb, Cb);
  if (useb) {
    k_pass1<1><<<dim3(NCH, BATCH), dim3(512), 0, stream>>>(x, Bb, lam, Z, bbuf);
    k_chain<<<dim3(BATCH), dim3(512), 0, stream>>>(Z, lamL, S0);
    k_pass2<1><<<dim3(NCH, BATCH), dim3(512), 0, stream>>>(x, Bb, Cb, lam, S0, bbuf, out, fin);
  } else {
    k_pass1<0><<<dim3(NCH, BATCH), dim3(512), 0, stream>>>(x, Bb, lam, Z, bbuf);
    k_chain<<<dim3(BATCH), dim3(512), 0, stream>>>(Z, lamL, S0);
    k_pass2<0><<<dim3(NCH, BATCH), dim3(512), 0, stream>>>(x, Bb, Cb, lam, S0, bbuf, out, fin);
  }
}